// Round 2
// baseline (121.505 us; speedup 1.0000x reference)
//
#include <hip/hip_runtime.h>
#include <hip/hip_bf16.h>
#include <stdint.h>

typedef __attribute__((ext_vector_type(8))) short short8;   // 8 bf16 (4 VGPR) MFMA operand
typedef __attribute__((ext_vector_type(4))) float floatx4;  // MFMA accumulator

#define MP 4096   // M' = BATCH*8  (rows m' = b*8+k)
#define NP 512    // N' = OUT_F    (cols = o)
#define BM 128
#define BN 64
#define BK 64     // K-slab per iter = 8 p * 8 j
#define KITER 64  // 4096 / BK

// sgn[k][j] = s(k^j, j) packed as bf16-sign XOR masks (2 lanes per u32:
// low half = even j, high half = odd j). Rows k=2m and k=2m+1 share a mask
// (verified against the transposition-count recurrence for all k,j).
__device__ __align__(16) const uint32_t SGN[4][4] = {
    {0x00000000u, 0x80000000u, 0x80000000u, 0x80008000u},  // k=0,1: + + + - + - - -
    {0x80000000u, 0x00000000u, 0x00000000u, 0x00008000u},  // k=2,3: + - + + + + - +
    {0x80000000u, 0x80008000u, 0x00000000u, 0x80000000u},  // k=4,5: + - - - + + + -
    {0x00000000u, 0x00008000u, 0x80000000u, 0x00000000u},  // k=6,7: + + - + + - + +
};

__device__ __forceinline__ uint32_t swap16(uint32_t a) { return (a >> 16) | (a << 16); }

__device__ __forceinline__ uint32_t pkbf(float a, float b) {
    unsigned short lo = __builtin_bit_cast(unsigned short, __float2bfloat16(a));
    unsigned short hi = __builtin_bit_cast(unsigned short, __float2bfloat16(b));
    return (uint32_t)lo | ((uint32_t)hi << 16);
}

// XOR-permute 8 packed bf16 by even k = 2*kp:  out[j] = in[j ^ k] (bits 1,2 of k)
__device__ __forceinline__ uint4 xperm2(uint4 v, int kp) {
    const bool s1 = (kp & 1) != 0;   // k bit1: j^2  (u32 x<->y, z<->w)
    uint32_t x1 = s1 ? v.y : v.x;
    uint32_t y1 = s1 ? v.x : v.y;
    uint32_t z1 = s1 ? v.w : v.z;
    uint32_t w1 = s1 ? v.z : v.w;
    const bool s2 = (kp & 2) != 0;   // k bit2: j^4  (pair swap)
    uint4 r;
    r.x = s2 ? z1 : x1;  r.y = s2 ? w1 : y1;
    r.z = s2 ? x1 : z1;  r.w = s2 ? y1 : w1;
    return r;
}

__global__ __launch_bounds__(512) void gp_linear_kernel(
    const float* __restrict__ xg_raw,   // x  f32 [512][512][8]
    const float* __restrict__ wg,       // W  f32 [512][512][8]
    const float* __restrict__ bias,     // b  f32 [512][8]
    float*       __restrict__ out)      // out f32 [512][512][8]
{
    // As[row=(b_l*8+k)][col=(p_l^k)*8 + j]  bf16, XOR-swizzled 16B chunks
    __shared__ __align__(16) unsigned short As[BM * BK];       // 16 KB
    // Bs[p_l][o_l][j]  bf16, linear
    __shared__ __align__(16) unsigned short Bs[8 * BN * 8];    // 8 KB

    const int t    = threadIdx.x;
    const int lane = t & 63;
    const int wave = t >> 6;      // 0..7

    const int m0 = blockIdx.y * BM;
    const int n0 = blockIdx.x * BN;

    // --- A staging mapping: 1024 chunk-rows/iter, 2 per thread (1 b, 2 k) ---
    const int ap  = t & 7;          // p_local 0..7
    const int akp = (t >> 3) & 3;   // k-pair -> k = 2*akp, 2*akp+1
    const int ab  = t >> 5;         // b_local 0..15
    const int ak0 = akp * 2;
    const uint4 mask = *(const uint4*)SGN[akp];

    // --- wave tiling: 8 waves = 4(m) x 2(n), each 32x32 = 2x2 frags 16x16 ---
    const int wm  = wave & 3;
    const int wn  = wave >> 2;
    const int l15 = lane & 15;
    const int q   = lane >> 4;

    floatx4 acc[2][2] = {};

    const float4* xg = (const float4*)xg_raw;   // 2 float4 = one x[b][p][0..7] chunk
    const int bg0 = m0 >> 3;

    float4 ax0, ax1, bw0, bw1;
    {   // preload kt = 0
        const size_t aidx = ((size_t)(bg0 + ab) * 512 + 0 + ap) * 2;
        ax0 = xg[aidx];  ax1 = xg[aidx + 1];
        const float* gsrc = wg + (((size_t)(0 + wave) * 512 + n0) << 3) + (lane << 3);
        bw0 = *(const float4*)gsrc;  bw1 = *(const float4*)(gsrc + 4);
    }

    for (int kt = 0; kt < KITER; ++kt) {
        __syncthreads();   // previous iter's frag reads done before overwrite

        // ---- A: cvt to bf16, XOR-permute + sign, 2 k-rows ----
        {
            uint4 v;
            v.x = pkbf(ax0.x, ax0.y);  v.y = pkbf(ax0.z, ax0.w);
            v.z = pkbf(ax1.x, ax1.y);  v.w = pkbf(ax1.z, ax1.w);
            uint4 pk = xperm2(v, akp);                 // permute for even k0
            uint4 r0, p1, r1;
            r0.x = pk.x ^ mask.x; r0.y = pk.y ^ mask.y;
            r0.z = pk.z ^ mask.z; r0.w = pk.w ^ mask.w;
            p1.x = swap16(pk.x);  p1.y = swap16(pk.y); // extra j^1 swap -> k0+1
            p1.z = swap16(pk.z);  p1.w = swap16(pk.w);
            r1.x = p1.x ^ mask.x; r1.y = p1.y ^ mask.y;
            r1.z = p1.z ^ mask.z; r1.w = p1.w ^ mask.w;
            const int row0 = ab * 8 + ak0;
            *(uint4*)&As[row0 * BK + ((ap ^ ak0) << 3)]             = r0;
            *(uint4*)&As[(row0 + 1) * BK + ((ap ^ (ak0 + 1)) << 3)] = r1;
        }

        // ---- B: cvt to bf16, linear store; thread t owns 8 floats ----
        {
            uint4 b0;
            b0.x = pkbf(bw0.x, bw0.y);  b0.y = pkbf(bw0.z, bw0.w);
            b0.z = pkbf(bw1.x, bw1.y);  b0.w = pkbf(bw1.z, bw1.w);
            *(uint4*)&Bs[t << 3] = b0;  // Bs[(wave*64+lane)*8 + 0..7]
        }

        __syncthreads();

        // ---- prefetch next iter's globals (overlap with MFMA below) ----
        if (kt + 1 < KITER) {
            const int p0n = (kt + 1) * 8;
            const size_t aidx = ((size_t)(bg0 + ab) * 512 + p0n + ap) * 2;
            ax0 = xg[aidx];  ax1 = xg[aidx + 1];
            const float* gsrc = wg + (((size_t)(p0n + wave) * 512 + n0) << 3) + (lane << 3);
            bw0 = *(const float4*)gsrc;  bw1 = *(const float4*)(gsrc + 4);
        }

        // ---- MFMA: 2 ksteps x (2 tm x 2 tn) 16x16x32 ----
        #pragma unroll
        for (int ks = 0; ks < 2; ++ks) {
            const int cb = ks * 4 + q;     // p-chunk 0..7 (K = cb*8 + j)
            short8 a[2], bfr[2];
            #pragma unroll
            for (int tm = 0; tm < 2; ++tm) {
                const int row = wm * 32 + tm * 16 + l15;
                a[tm] = *(const short8*)&As[row * BK + ((cb ^ (l15 & 7)) << 3)];
            }
            #pragma unroll
            for (int tn = 0; tn < 2; ++tn) {
                const int nl = wn * 32 + tn * 16 + l15;
                bfr[tn] = *(const short8*)&Bs[((cb * BN) + nl) << 3];
            }
            #pragma unroll
            for (int tm = 0; tm < 2; ++tm)
                #pragma unroll
                for (int tn = 0; tn < 2; ++tn)
                    acc[tm][tn] = __builtin_amdgcn_mfma_f32_16x16x32_bf16(
                        a[tm], bfr[tn], acc[tm][tn], 0, 0, 0);
        }
    }

    // ---- epilogue: bias + f32 store; m' = b*8+k, out[b][o][k] ----
    #pragma unroll
    for (int tm = 0; tm < 2; ++tm) {
        #pragma unroll
        for (int tn = 0; tn < 2; ++tn) {
            const int n = n0 + wn * 32 + tn * 16 + l15;
            #pragma unroll
            for (int r = 0; r < 4; ++r) {
                const int m  = m0 + wm * 32 + tm * 16 + q * 4 + r;
                const int bi = m >> 3;
                const int k  = m & 7;
                out[(size_t)bi * 4096 + n * 8 + k] = acc[tm][tn][r] + bias[n * 8 + k];
            }
        }
    }
}

extern "C" void kernel_launch(void* const* d_in, const int* in_sizes, int n_in,
                              void* d_out, int out_size, void* d_ws, size_t ws_size,
                              hipStream_t stream) {
    const float* x  = (const float*)d_in[0];
    const float* W  = (const float*)d_in[1];
    const float* bb = (const float*)d_in[2];
    // d_in[3] = G: exact Cl(3,0) Cayley table, hard-coded into SGN/xperm2 — unused.
    float* out = (float*)d_out;

    dim3 grid(NP / BN, MP / BM);   // (8, 32) = 256 blocks of 512 threads
    gp_linear_kernel<<<grid, dim3(512), 0, stream>>>(x, W, bb, out);
}

// Round 3
// 95.214 us; speedup vs baseline: 1.2761x; 1.2761x over previous
//
#include <hip/hip_runtime.h>
#include <hip/hip_bf16.h>
#include <stdint.h>

typedef __attribute__((ext_vector_type(8))) short short8;   // 8 bf16 MFMA operand
typedef __attribute__((ext_vector_type(4))) float floatx4;  // MFMA accumulator

__device__ __forceinline__ uint32_t pkbf(float a, float b) {
    unsigned short lo = __builtin_bit_cast(unsigned short, __float2bfloat16(a));
    unsigned short hi = __builtin_bit_cast(unsigned short, __float2bfloat16(b));
    return (uint32_t)lo | ((uint32_t)hi << 16);
}

// reference sign: G[a][b][a^b] = (-1)^(transposition count)
__device__ __forceinline__ int gp_sign_neg(int a, int b) {
    int sw = 0, tt = a >> 1;
    while (tt) { sw += __popc(tt & b); tt >>= 1; }
    return sw & 1;
}

// ---------------- Pass 1a: xT[b][i][p] = bf16(x[b][p][i]) ----------------
__global__ __launch_bounds__(256) void make_xT(const float* __restrict__ x,
                                               unsigned short* __restrict__ xT) {
    __shared__ unsigned short tile[8 * 512];   // [i][p]
    const int b = blockIdx.x;
    const int t = threadIdx.x;
    const float4* xb = (const float4*)(x + (size_t)b * 4096);
    float4 f0 = xb[4 * t + 0], f1 = xb[4 * t + 1], f2 = xb[4 * t + 2], f3 = xb[4 * t + 3];
    float a0[8] = {f0.x, f0.y, f0.z, f0.w, f1.x, f1.y, f1.z, f1.w};  // p = 2t
    float a1[8] = {f2.x, f2.y, f2.z, f2.w, f3.x, f3.y, f3.z, f3.w};  // p = 2t+1
    uint32_t* tl = (uint32_t*)tile;
    #pragma unroll
    for (int i = 0; i < 8; ++i)
        tl[i * 256 + t] = pkbf(a0[i], a1[i]);
    __syncthreads();
    uint4* dst = (uint4*)(xT + (size_t)b * 4096);
    const uint4* src = (const uint4*)tile;
    dst[t] = src[t];
    dst[t + 256] = src[t + 256];
}

// ---------------- Pass 1b: WT[j][o][p] = bf16(W[p][o][j]) ----------------
__global__ __launch_bounds__(256) void make_WT(const float* __restrict__ W,
                                               unsigned short* __restrict__ WT) {
    __shared__ unsigned short tile[8 * 64 * 24];  // [j][o][p16 pad->24]
    const int t = threadIdx.x;
    const int o0 = blockIdx.x * 64, p0 = blockIdx.y * 16;
    const int o = t & 63, pq = t >> 6;            // p = p0 + pq*4 + s
    float v[4][8];
    #pragma unroll
    for (int s = 0; s < 4; ++s) {
        const float4* src = (const float4*)(W + ((size_t)(p0 + pq * 4 + s) * 512 + o0 + o) * 8);
        float4 lo = src[0], hi = src[1];
        v[s][0] = lo.x; v[s][1] = lo.y; v[s][2] = lo.z; v[s][3] = lo.w;
        v[s][4] = hi.x; v[s][5] = hi.y; v[s][6] = hi.z; v[s][7] = hi.w;
    }
    #pragma unroll
    for (int j = 0; j < 8; ++j) {
        uint32_t* p = (uint32_t*)&tile[(j * 64 + o) * 24 + pq * 4];
        p[0] = pkbf(v[0][j], v[1][j]);
        p[1] = pkbf(v[2][j], v[3][j]);
    }
    __syncthreads();
    #pragma unroll
    for (int si = 0; si < 4; ++si) {
        int c = si * 256 + t;                      // 1024 chunks of 16 B
        int j = c >> 7, oo = (c >> 1) & 63, h = c & 1;
        uint4 val = *(const uint4*)&tile[(j * 64 + oo) * 24 + h * 8];
        *(uint4*)&WT[((size_t)j * 512 + o0 + oo) * 512 + p0 + h * 8] = val;
    }
}

// ---------------- Pass 2: out[(b,k)][o] = sum_{j,p} s(k^j,j) xT[b][k^j][p] WT[j][o][p] ----------------
#define GLL(src, dstoff) \
    __builtin_amdgcn_global_load_lds((const __attribute__((address_space(1))) uint32_t*)(src), \
        (__attribute__((address_space(3))) uint32_t*)(smem + (dstoff)), 16, 0, 0)

__global__ __launch_bounds__(512, 2) void gp_gemm(
    const unsigned short* __restrict__ xT,   // [512][8][512] bf16
    const unsigned short* __restrict__ WT,   // [8][512][512] bf16
    const float* __restrict__ bias,          // [512][8] f32
    float*       __restrict__ out)           // [512][512][8] f32
{
    // buf k at smem + k*40960: A 512 slots x 16B (b,i,c), B at +8192: 2048 slots (j,o,c)
    __shared__ __align__(16) unsigned char smem[81920];
    const int t = threadIdx.x;
    const int lane = t & 63;
    const int wave = t >> 6;
    const int wm = wave & 1;        // spatial row half
    const int g  = wave >> 1;       // K-group 0..3
    const int j0 = (g & 1) * 4;     // j-half
    const int c0 = (g >> 1) * 2;    // p-chunk pair {c0, c0+1}
    const int l15 = lane & 15;
    const int q = lane >> 4;

    // XCD-aware tile swizzle: per-XCD 2 n-tiles x 16 m-tiles (~3MB working set)
    const int lin = blockIdx.y * 32 + blockIdx.x;
    const int cx = lin & 7, sx = lin >> 3;
    const int n_tile = (cx & 3) * 2 + (sx & 1);
    const int m_tile = (cx >> 2) * 16 + (sx >> 1);
    const int m0 = m_tile * 128;
    const int n0 = n_tile * 64;
    const int bg0 = m0 >> 3;

    // ---- staging source addresses (swizzle folded into source gather) ----
    const int sa_b = t >> 5, sa_i = (t >> 2) & 7, sa_cs = t & 3;
    const int sa_cl = sa_cs ^ ((sa_i & 3) ^ ((sa_i >> 2) & 1));
    const unsigned short* a_src = xT + ((size_t)(bg0 + sa_b) * 8 + sa_i) * 512 + sa_cl * 8;
    const unsigned short* b_srcs[4];
    #pragma unroll
    for (int si = 0; si < 4; ++si) {
        int s = si * 512 + t;
        int j = s >> 8, n = (s >> 2) & 63, cs = s & 3;
        int cl = cs ^ ((n >> 1) & 3);
        b_srcs[si] = WT + ((size_t)j * 512 + n0 + n) * 512 + cl * 8;
    }

    // ---- compute-side lane constants ----
    const int k_l = l15 & 7;
    const int j_l = j0 + q;              // this lane's j for all its K-elems
    const int i_l = k_l ^ j_l;           // xT row
    const uint32_t xmask = gp_sign_neg(i_l, j_l) ? 0x80008000u : 0u;
    const int Sil = (i_l & 3) ^ ((i_l >> 2) & 1);
    const int a_off = (((wm * 8 + (l15 >> 3)) * 8 + i_l) * 4 + (c0 ^ Sil)) * 16;
    const int b_off = 8192 + ((j_l * 64 + l15) * 4 + (c0 ^ ((l15 >> 1) & 3))) * 16;

    floatx4 acc[4][4] = {};
    const int wbase = wave * 1024;

    // preload kt=0 into buf 0
    GLL(a_src, wbase);
    #pragma unroll
    for (int si = 0; si < 4; ++si)
        GLL(b_srcs[si], 8192 + si * 8192 + wbase);

    for (int kt = 0; kt < 16; ++kt) {
        __syncthreads();                       // drains vmcnt: buf[kt] ready
        const int cur = (kt & 1) * 40960;
        if (kt + 1 < 16) {                     // prefetch next slab, other buffer
            const int nxt = ((kt + 1) & 1) * 40960;
            const int poff = (kt + 1) * 32;
            GLL(a_src + poff, nxt + wbase);
            #pragma unroll
            for (int si = 0; si < 4; ++si)
                GLL(b_srcs[si] + poff, nxt + 8192 + si * 8192 + wbase);
        }
        #pragma unroll
        for (int ss = 0; ss < 2; ++ss) {       // 2 ksteps (p-chunks c0, c0+1)
            const int ax = ss * 16;            // chunk pair differs in slot bit0
            short8 af[4], bf[4];
            #pragma unroll
            for (int tm = 0; tm < 4; ++tm) {
                af[tm] = *(const short8*)&smem[cur + ((a_off + tm * 1024) ^ ax)];
                uint32_t* u = (uint32_t*)&af[tm];
                u[0] ^= xmask; u[1] ^= xmask; u[2] ^= xmask; u[3] ^= xmask;
            }
            #pragma unroll
            for (int tn = 0; tn < 4; ++tn)
                bf[tn] = *(const short8*)&smem[cur + ((b_off + tn * 1024) ^ ax)];
            #pragma unroll
            for (int tm = 0; tm < 4; ++tm)
                #pragma unroll
                for (int tn = 0; tn < 4; ++tn)
                    acc[tm][tn] = __builtin_amdgcn_mfma_f32_16x16x32_bf16(
                        af[tm], bf[tn], acc[tm][tn], 0, 0, 0);
        }
    }

    // ---- K-group tree reduction through LDS ----
    __syncthreads();
    float* red = (float*)smem;
    if (g >= 2) {
        float* r = red + (wm * 2 + (g - 2)) * 4096;
        #pragma unroll
        for (int f = 0; f < 16; ++f)
            *(floatx4*)&r[f * 256 + lane * 4] = acc[f >> 2][f & 3];
    }
    __syncthreads();
    if (g < 2) {
        const float* r = red + (wm * 2 + g) * 4096;
        #pragma unroll
        for (int f = 0; f < 16; ++f)
            acc[f >> 2][f & 3] += *(const floatx4*)&r[f * 256 + lane * 4];
    }
    __syncthreads();
    if (g == 1) {
        float* r = red + wm * 4096;
        #pragma unroll
        for (int f = 0; f < 16; ++f)
            *(floatx4*)&r[f * 256 + lane * 4] = acc[f >> 2][f & 3];
    }
    __syncthreads();
    if (g == 0) {
        const float* r = red + wm * 4096;
        #pragma unroll
        for (int f = 0; f < 16; ++f)
            acc[f >> 2][f & 3] += *(const floatx4*)&r[f * 256 + lane * 4];
        #pragma unroll
        for (int tm = 0; tm < 4; ++tm)
            #pragma unroll
            for (int tn = 0; tn < 4; ++tn) {
                const int n = n0 + tn * 16 + l15;
                #pragma unroll
                for (int rr = 0; rr < 4; ++rr) {
                    const int m = m0 + wm * 64 + tm * 16 + q * 4 + rr;
                    const int bi = m >> 3, k = m & 7;
                    out[(size_t)bi * 4096 + n * 8 + k] = acc[tm][tn][rr] + bias[n * 8 + k];
                }
            }
    }
}

// ---------------- Fallback (verified round-2 kernel) if ws too small ----------------
__device__ __align__(16) const uint32_t SGN[4][4] = {
    {0x00000000u, 0x80000000u, 0x80000000u, 0x80008000u},
    {0x80000000u, 0x00000000u, 0x00000000u, 0x00008000u},
    {0x80000000u, 0x80008000u, 0x00000000u, 0x80000000u},
    {0x00000000u, 0x00008000u, 0x80000000u, 0x00000000u},
};
__device__ __forceinline__ uint32_t swap16(uint32_t a) { return (a >> 16) | (a << 16); }
__device__ __forceinline__ uint4 xperm2(uint4 v, int kp) {
    const bool s1 = (kp & 1) != 0;
    uint32_t x1 = s1 ? v.y : v.x, y1 = s1 ? v.x : v.y, z1 = s1 ? v.w : v.z, w1 = s1 ? v.z : v.w;
    const bool s2 = (kp & 2) != 0;
    uint4 r; r.x = s2 ? z1 : x1; r.y = s2 ? w1 : y1; r.z = s2 ? x1 : z1; r.w = s2 ? y1 : w1;
    return r;
}
__global__ __launch_bounds__(512) void gp_linear_legacy(
    const float* __restrict__ xg_raw, const float* __restrict__ wg,
    const float* __restrict__ bias, float* __restrict__ out)
{
    __shared__ __align__(16) unsigned short As[128 * 64];
    __shared__ __align__(16) unsigned short Bs[8 * 64 * 8];
    const int t = threadIdx.x, lane = t & 63, wave = t >> 6;
    const int m0 = blockIdx.y * 128, n0 = blockIdx.x * 64;
    const int ap = t & 7, akp = (t >> 3) & 3, ab = t >> 5, ak0 = akp * 2;
    const uint4 mask = *(const uint4*)SGN[akp];
    const int wm = wave & 3, wn = wave >> 2, l15 = lane & 15, q = lane >> 4;
    floatx4 acc[2][2] = {};
    const float4* xg = (const float4*)xg_raw;
    const int bg0 = m0 >> 3;
    float4 ax0, ax1, bw0, bw1;
    {
        const size_t aidx = ((size_t)(bg0 + ab) * 512 + ap) * 2;
        ax0 = xg[aidx]; ax1 = xg[aidx + 1];
        const float* gsrc = wg + (((size_t)wave * 512 + n0) << 3) + (lane << 3);
        bw0 = *(const float4*)gsrc; bw1 = *(const float4*)(gsrc + 4);
    }
    for (int kt = 0; kt < 64; ++kt) {
        __syncthreads();
        {
            uint4 v;
            v.x = pkbf(ax0.x, ax0.y); v.y = pkbf(ax0.z, ax0.w);
            v.z = pkbf(ax1.x, ax1.y); v.w = pkbf(ax1.z, ax1.w);
            uint4 pk = xperm2(v, akp), r0, p1, r1;
            r0.x = pk.x ^ mask.x; r0.y = pk.y ^ mask.y; r0.z = pk.z ^ mask.z; r0.w = pk.w ^ mask.w;
            p1.x = swap16(pk.x); p1.y = swap16(pk.y); p1.z = swap16(pk.z); p1.w = swap16(pk.w);
            r1.x = p1.x ^ mask.x; r1.y = p1.y ^ mask.y; r1.z = p1.z ^ mask.z; r1.w = p1.w ^ mask.w;
            const int row0 = ab * 8 + ak0;
            *(uint4*)&As[row0 * 64 + ((ap ^ ak0) << 3)] = r0;
            *(uint4*)&As[(row0 + 1) * 64 + ((ap ^ (ak0 + 1)) << 3)] = r1;
        }
        {
            uint4 b0;
            b0.x = pkbf(bw0.x, bw0.y); b0.y = pkbf(bw0.z, bw0.w);
            b0.z = pkbf(bw1.x, bw1.y); b0.w = pkbf(bw1.z, bw1.w);
            *(uint4*)&Bs[t << 3] = b0;
        }
        __syncthreads();
        if (kt + 1 < 64) {
            const int p0n = (kt + 1) * 8;
            const size_t aidx = ((size_t)(bg0 + ab) * 512 + p0n + ap) * 2;
            ax0 = xg[aidx]; ax1 = xg[aidx + 1];
            const float* gsrc = wg + (((size_t)(p0n + wave) * 512 + n0) << 3) + (lane << 3);
            bw0 = *(const float4*)gsrc; bw1 = *(const float4*)(gsrc + 4);
        }
        #pragma unroll
        for (int ks = 0; ks < 2; ++ks) {
            const int cb = ks * 4 + q;
            short8 a[2], bfr[2];
            #pragma unroll
            for (int tm = 0; tm < 2; ++tm) {
                const int row = wm * 32 + tm * 16 + l15;
                a[tm] = *(const short8*)&As[row * 64 + ((cb ^ (l15 & 7)) << 3)];
            }
            #pragma unroll
            for (int tn = 0; tn < 2; ++tn) {
                const int nl = wn * 32 + tn * 16 + l15;
                bfr[tn] = *(const short8*)&Bs[((cb * 64) + nl) << 3];
            }
            #pragma unroll
            for (int tm = 0; tm < 2; ++tm)
                #pragma unroll
                for (int tn = 0; tn < 2; ++tn)
                    acc[tm][tn] = __builtin_amdgcn_mfma_f32_16x16x32_bf16(a[tm], bfr[tn], acc[tm][tn], 0, 0, 0);
        }
    }
    #pragma unroll
    for (int tm = 0; tm < 2; ++tm)
        #pragma unroll
        for (int tn = 0; tn < 2; ++tn) {
            const int n = n0 + wn * 32 + tn * 16 + l15;
            #pragma unroll
            for (int r = 0; r < 4; ++r) {
                const int m = m0 + wm * 32 + tm * 16 + q * 4 + r;
                const int bi = m >> 3, k = m & 7;
                out[(size_t)bi * 4096 + n * 8 + k] = acc[tm][tn][r] + bias[n * 8 + k];
            }
        }
}

extern "C" void kernel_launch(void* const* d_in, const int* in_sizes, int n_in,
                              void* d_out, int out_size, void* d_ws, size_t ws_size,
                              hipStream_t stream) {
    const float* x  = (const float*)d_in[0];
    const float* W  = (const float*)d_in[1];
    const float* bb = (const float*)d_in[2];
    float* out = (float*)d_out;

    if (ws_size >= 2u * 512u * 8u * 512u * sizeof(unsigned short)) {
        unsigned short* xT = (unsigned short*)d_ws;
        unsigned short* WT = xT + 512 * 8 * 512;
        make_xT<<<512, 256, 0, stream>>>(x, xT);
        make_WT<<<dim3(8, 32), 256, 0, stream>>>(W, WT);
        gp_gemm<<<dim3(32, 8), 512, 0, stream>>>(xT, WT, bb, out);
    } else {
        gp_linear_legacy<<<dim3(8, 32), dim3(512), 0, stream>>>(x, W, bb, out);
    }
}

// Round 5
// 94.054 us; speedup vs baseline: 1.2919x; 1.0123x over previous
//
#include <hip/hip_runtime.h>
#include <hip/hip_bf16.h>
#include <stdint.h>

typedef __attribute__((ext_vector_type(8))) short short8;   // 8 bf16 MFMA operand
typedef __attribute__((ext_vector_type(4))) float floatx4;  // MFMA accumulator

__device__ __forceinline__ unsigned short bfu(float a) {
    return __builtin_bit_cast(unsigned short, __float2bfloat16(a));
}
__device__ __forceinline__ uint32_t pkbf(float a, float b) {
    return (uint32_t)bfu(a) | ((uint32_t)bfu(b) << 16);
}

// =====================  Cl(3,0) -> M2(C) (Pauli) isomorphism  =====================
// blades: a0=1 a1=e1 a2=e2 a3=e12 a4=e3 a5=e13 a6=e23 a7=e123
// Re m00=a0+a4 Im m00=a3+a7 | Re m01=a1-a5 Im m01=a6-a2
// Re m10=a1+a5 Im m10=a6+a2 | Re m11=a0-a4 Im m11=a7-a3
// K index: k = part*1024 + 2p + s   (s = Mw row / Mx col, minor)
// Abuf[1024][2048]: row 2b+r, col k = (part? Im:Re) Mx[b,p](r,s)
// BT  [2048][2048]: row n = 4o+2partN+c, col k =
//     part0: (partN? Im:Re) Mw[p,o](s,c);  part1: (partN? Re:-Im) Mw[p,o](s,c)
// Then C[2b+r][4o+2partN+c] = (partN? Im:Re) of (Mx·Mw)(r,c).

// ---------------- Pass 1a: x -> Abuf [M=1024][K=2048] ----------------
__global__ __launch_bounds__(256) void pack_x(
    const float* __restrict__ x, unsigned short* __restrict__ Abuf)
{
    __shared__ unsigned short TX[4][1024];   // [r*2+part][2p+s]
    const int b = blockIdx.x;
    const int t = threadIdx.x;
    const float4* src = (const float4*)(x + ((size_t)b * 512 + 2 * t) * 8);
    float4 f[4] = {src[0], src[1], src[2], src[3]};
    #pragma unroll
    for (int pp = 0; pp < 2; ++pp) {
        const float a0 = f[2*pp].x, a1 = f[2*pp].y, a2 = f[2*pp].z, a3 = f[2*pp].w;
        const float a4 = f[2*pp+1].x, a5 = f[2*pp+1].y, a6 = f[2*pp+1].z, a7 = f[2*pp+1].w;
        const int c = 4 * t + 2 * pp;
        TX[0][c] = bfu(a0 + a4); TX[0][c+1] = bfu(a1 - a5);   // Re Mx(0,s)
        TX[1][c] = bfu(a3 + a7); TX[1][c+1] = bfu(a6 - a2);   // Im Mx(0,s)
        TX[2][c] = bfu(a1 + a5); TX[2][c+1] = bfu(a0 - a4);   // Re Mx(1,s)
        TX[3][c] = bfu(a6 + a2); TX[3][c+1] = bfu(a7 - a3);   // Im Mx(1,s)
    }
    __syncthreads();
    const int tr = t >> 6, off = (t & 63) * 16;
    uint4* dst = (uint4*)(Abuf + (size_t)(2*b + (tr >> 1)) * 2048 + (tr & 1) * 1024 + off);
    const uint4* s4 = (const uint4*)&TX[tr][off];
    dst[0] = s4[0]; dst[1] = s4[1];
}

// ---------------- Pass 1b: W -> BT [N=2048][K=2048] (register transpose) ----------------
// block: p in [pbase, pbase+64), o in [o0, o0+16); thread: p-chunk of 4 (pc=t&15), o = o0+(t>>4)
__global__ __launch_bounds__(256) void pack_w(
    const float* __restrict__ W, unsigned short* __restrict__ BT)
{
    const int wb = blockIdx.x;            // 0..255
    const int pbase = (wb & 7) * 64;
    const int o0 = (wb >> 3) * 16;
    const int t = threadIdx.x;
    const int pc = t & 15;
    const int o = o0 + (t >> 4);
    float R[4][2][2], I[4][2][2];         // [u][s][c] = Re/Im Mw(s,c) for p = pbase+pc*4+u
    #pragma unroll
    for (int u = 0; u < 4; ++u) {
        const float4* src = (const float4*)(W + ((size_t)(pbase + pc * 4 + u) * 512 + o) * 8);
        float4 lo = src[0], hi = src[1];  // a0..a3 | a4..a7
        R[u][0][0] = lo.x + hi.x;  I[u][0][0] = lo.w + hi.w;
        R[u][0][1] = lo.y - hi.y;  I[u][0][1] = hi.z - lo.z;
        R[u][1][0] = lo.y + hi.y;  I[u][1][0] = hi.z + lo.z;
        R[u][1][1] = lo.x - hi.x;  I[u][1][1] = hi.w - lo.w;
    }
    const int kbase = 2 * pbase + pc * 8;   // 16B-aligned k-run of 8 (4 p x 2 s)
    #pragma unroll
    for (int part = 0; part < 2; ++part)
        #pragma unroll
        for (int pN = 0; pN < 2; ++pN)
            #pragma unroll
            for (int c = 0; c < 2; ++c) {
                uint4 v; uint32_t* vv = (uint32_t*)&v;
                #pragma unroll
                for (int u = 0; u < 4; ++u) {
                    const float v0 = (part == 0) ? (pN ? I[u][0][c] : R[u][0][c])
                                                 : (pN ? R[u][0][c] : -I[u][0][c]);
                    const float v1 = (part == 0) ? (pN ? I[u][1][c] : R[u][1][c])
                                                 : (pN ? R[u][1][c] : -I[u][1][c]);
                    vv[u] = pkbf(v0, v1);
                }
                const int n = 4 * o + 2 * pN + c;
                *(uint4*)&BT[(size_t)n * 2048 + part * 1024 + kbase] = v;
            }
}

// =====================  Pass 2: C[1024][2048] = A·B^T, inverse map + bias  =====================
#define GLL(src, dstoff) \
    __builtin_amdgcn_global_load_lds((const __attribute__((address_space(1))) uint32_t*)(src), \
        (__attribute__((address_space(3))) uint32_t*)(smem + (dstoff)), 16, 0, 0)

__global__ __launch_bounds__(512, 2) void iso_gemm(
    const unsigned short* __restrict__ AB,   // [1024][2048] bf16, M-major K-minor
    const unsigned short* __restrict__ BB,   // [2048][2048] bf16, N-major K-minor
    const float* __restrict__ bias,          // [512][8] f32
    float*       __restrict__ out)           // [512][512][8] f32
{
    // buf kt&1 at *49152: A 64 rows x 16 slots x 16B (16 KB); B at +16384: 128 rows (32 KB)
    __shared__ __align__(16) unsigned char smem[98304];
    const int t = threadIdx.x, lane = t & 63, wave = t >> 6;
    const int wn = wave & 1;        // spatial n-half (64 cols)
    const int g  = wave >> 1;       // K-group 0..3
    const int l15 = lane & 15, q = lane >> 4;

    // XCD swizzle
    const int lin = blockIdx.y * 16 + blockIdx.x;
    const int xcd = lin & 7, sx = lin >> 3;
    const int tn = (xcd & 3) * 4 + (sx & 3);
    const int tm = (xcd >> 2) * 8 + (sx >> 2);
    const int m0 = tm * 64, v0 = tn * 128;

    // staging: per wave 2 A-GLL + 4 B-GLL; LDS slot holds chunk (slot ^ (row&7))
    const unsigned short* a_srcs[2]; int a_dst[2];
    #pragma unroll
    for (int i = 0; i < 2; ++i) {
        const int sl = (wave * 2 + i) * 64 + lane;
        const int row = sl >> 4, slot = sl & 15, chunk = slot ^ (row & 7);
        a_srcs[i] = AB + (size_t)(m0 + row) * 2048 + chunk * 8;
        a_dst[i] = (wave * 2 + i) * 1024;
    }
    const unsigned short* b_srcs[4]; int b_dst[4];
    #pragma unroll
    for (int i = 0; i < 4; ++i) {
        const int sl = (wave * 4 + i) * 64 + lane;
        const int row = sl >> 4, slot = sl & 15, chunk = slot ^ (row & 7);
        b_srcs[i] = BB + (size_t)(v0 + row) * 2048 + chunk * 8;
        b_dst[i] = 16384 + (wave * 4 + i) * 1024;
    }

    // frag-read constants: chunk = g*4+q, slot = chunk ^ (l15&7)
    const int chunk = g * 4 + q;
    const int slot = chunk ^ (l15 & 7);
    const int a_off = l15 * 256 + slot * 16;
    const int b_off = 16384 + (wn * 64 + l15) * 256 + slot * 16;

    floatx4 acc[4][4] = {};

    #pragma unroll
    for (int i = 0; i < 2; ++i) GLL(a_srcs[i], a_dst[i]);
    #pragma unroll
    for (int i = 0; i < 4; ++i) GLL(b_srcs[i], b_dst[i]);

    for (int kt = 0; kt < 16; ++kt) {
        __syncthreads();                         // drains vmcnt: buf[kt] ready
        const int cur = (kt & 1) * 49152;
        if (kt + 1 < 16) {
            const int nxt = ((kt + 1) & 1) * 49152;
            const int poff = (kt + 1) * 128;
            #pragma unroll
            for (int i = 0; i < 2; ++i) GLL(a_srcs[i] + poff, nxt + a_dst[i]);
            #pragma unroll
            for (int i = 0; i < 4; ++i) GLL(b_srcs[i] + poff, nxt + b_dst[i]);
        }
        short8 af[4], bf[4];
        #pragma unroll
        for (int fm = 0; fm < 4; ++fm)
            af[fm] = *(const short8*)&smem[cur + a_off + fm * 4096];
        #pragma unroll
        for (int fn = 0; fn < 4; ++fn)
            bf[fn] = *(const short8*)&smem[cur + b_off + fn * 4096];
        #pragma unroll
        for (int fm = 0; fm < 4; ++fm)
            #pragma unroll
            for (int fn = 0; fn < 4; ++fn)
                acc[fm][fn] = __builtin_amdgcn_mfma_f32_16x16x32_bf16(
                    af[fm], bf[fn], acc[fm][fn], 0, 0, 0);
    }

    // ---- 4-way K-group tree reduction ----
    __syncthreads();
    float* red = (float*)smem;
    if (g >= 2) {
        float* r = red + (wn * 2 + (g - 2)) * 4096;
        #pragma unroll
        for (int f = 0; f < 16; ++f)
            *(floatx4*)&r[f * 256 + lane * 4] = acc[f >> 2][f & 3];
    }
    __syncthreads();
    if (g < 2) {
        const float* r = red + (wn * 2 + g) * 4096;
        #pragma unroll
        for (int f = 0; f < 16; ++f)
            acc[f >> 2][f & 3] += *(const floatx4*)&r[f * 256 + lane * 4];
    }
    __syncthreads();
    if (g == 1) {
        float* r = red + wn * 4096;
        #pragma unroll
        for (int f = 0; f < 16; ++f)
            *(floatx4*)&r[f * 256 + lane * 4] = acc[f >> 2][f & 3];
    }
    __syncthreads();
    float* Cf = (float*)(smem + 32768);          // [64][130] f32
    if (g == 0) {
        const float* r = red + wn * 4096;
        #pragma unroll
        for (int f = 0; f < 16; ++f)
            acc[f >> 2][f & 3] += *(const floatx4*)&r[f * 256 + lane * 4];
        #pragma unroll
        for (int fm = 0; fm < 4; ++fm)
            #pragma unroll
            for (int fn = 0; fn < 4; ++fn)
                #pragma unroll
                for (int rr = 0; rr < 4; ++rr) {
                    const int row = fm * 16 + q * 4 + rr;
                    const int col = wn * 64 + fn * 16 + l15;
                    Cf[row * 130 + col] = acc[fm][fn][rr];
                }
    }
    __syncthreads();
    // ---- inverse map + bias: 32 b x 32 o per block ----
    const int b0 = m0 >> 1, o0 = v0 >> 2;
    #pragma unroll
    for (int rnd = 0; rnd < 2; ++rnd) {
        const int pi = rnd * 512 + t;
        const int o_l = pi & 31, b_l = pi >> 5;
        const float* r0 = &Cf[(2 * b_l) * 130 + 4 * o_l];
        const float* r1 = r0 + 130;
        const float Cr00 = r0[0], Cr01 = r0[1], Ci00 = r0[2], Ci01 = r0[3];
        const float Cr10 = r1[0], Cr11 = r1[1], Ci10 = r1[2], Ci11 = r1[3];
        const float a0 = 0.5f * (Cr00 + Cr11), a7 = 0.5f * (Ci00 + Ci11);
        const float a4 = 0.5f * (Cr00 - Cr11), a3 = 0.5f * (Ci00 - Ci11);
        const float a1 = 0.5f * (Cr01 + Cr10), a6 = 0.5f * (Ci01 + Ci10);
        const float a2 = 0.5f * (Ci10 - Ci01), a5 = 0.5f * (Cr10 - Cr01);
        const int o = o0 + o_l, b = b0 + b_l;
        const float* bp = bias + o * 8;
        float4 lo = {a0 + bp[0], a1 + bp[1], a2 + bp[2], a3 + bp[3]};
        float4 hi = {a4 + bp[4], a5 + bp[5], a6 + bp[6], a7 + bp[7]};
        float* op = out + ((size_t)b * 512 + o) * 8;
        *(float4*)op = lo;
        *(float4*)(op + 4) = hi;
    }
}

// =====================  Fallback (verified round-2 kernel)  =====================
__device__ __align__(16) const uint32_t SGN[4][4] = {
    {0x00000000u, 0x80000000u, 0x80000000u, 0x80008000u},
    {0x80000000u, 0x00000000u, 0x00000000u, 0x00008000u},
    {0x80000000u, 0x80008000u, 0x00000000u, 0x80000000u},
    {0x00000000u, 0x00008000u, 0x80000000u, 0x00000000u},
};
__device__ __forceinline__ uint32_t swap16(uint32_t a) { return (a >> 16) | (a << 16); }
__device__ __forceinline__ uint4 xperm2(uint4 v, int kp) {
    const bool s1 = (kp & 1) != 0;
    uint32_t x1 = s1 ? v.y : v.x, y1 = s1 ? v.x : v.y, z1 = s1 ? v.w : v.z, w1 = s1 ? v.z : v.w;
    const bool s2 = (kp & 2) != 0;
    uint4 r; r.x = s2 ? z1 : x1; r.y = s2 ? w1 : y1; r.z = s2 ? x1 : z1; r.w = s2 ? y1 : w1;
    return r;
}
__global__ __launch_bounds__(512) void gp_linear_legacy(
    const float* __restrict__ xg_raw, const float* __restrict__ wg,
    const float* __restrict__ bias, float* __restrict__ out)
{
    __shared__ __align__(16) unsigned short As[128 * 64];
    __shared__ __align__(16) unsigned short Bs[8 * 64 * 8];
    const int t = threadIdx.x, lane = t & 63, wave = t >> 6;
    const int m0 = blockIdx.y * 128, n0 = blockIdx.x * 64;
    const int ap = t & 7, akp = (t >> 3) & 3, ab = t >> 5, ak0 = akp * 2;
    const uint4 mask = *(const uint4*)SGN[akp];
    const int wm = wave & 3, wnn = wave >> 2, l15 = lane & 15, q = lane >> 4;
    floatx4 acc[2][2] = {};
    const float4* xg = (const float4*)xg_raw;
    const int bg0 = m0 >> 3;
    float4 ax0, ax1, bw0, bw1;
    {
        const size_t aidx = ((size_t)(bg0 + ab) * 512 + ap) * 2;
        ax0 = xg[aidx]; ax1 = xg[aidx + 1];
        const float* gsrc = wg + (((size_t)wave * 512 + n0) << 3) + (lane << 3);
        bw0 = *(const float4*)gsrc; bw1 = *(const float4*)(gsrc + 4);
    }
    for (int kt = 0; kt < 64; ++kt) {
        __syncthreads();
        {
            uint4 v;
            v.x = pkbf(ax0.x, ax0.y); v.y = pkbf(ax0.z, ax0.w);
            v.z = pkbf(ax1.x, ax1.y); v.w = pkbf(ax1.z, ax1.w);
            uint4 pk = xperm2(v, akp), r0, p1, r1;
            r0.x = pk.x ^ mask.x; r0.y = pk.y ^ mask.y; r0.z = pk.z ^ mask.z; r0.w = pk.w ^ mask.w;
            p1.x = swap16(pk.x); p1.y = swap16(pk.y); p1.z = swap16(pk.z); p1.w = swap16(pk.w);
            r1.x = p1.x ^ mask.x; r1.y = p1.y ^ mask.y; r1.z = p1.z ^ mask.z; r1.w = p1.w ^ mask.w;
            const int row0 = ab * 8 + ak0;
            *(uint4*)&As[row0 * 64 + ((ap ^ ak0) << 3)] = r0;
            *(uint4*)&As[(row0 + 1) * 64 + ((ap ^ (ak0 + 1)) << 3)] = r1;
        }
        {
            uint4 b0;
            b0.x = pkbf(bw0.x, bw0.y); b0.y = pkbf(bw0.z, bw0.w);
            b0.z = pkbf(bw1.x, bw1.y); b0.w = pkbf(bw1.z, bw1.w);
            *(uint4*)&Bs[t << 3] = b0;
        }
        __syncthreads();
        if (kt + 1 < 64) {
            const int p0n = (kt + 1) * 8;
            const size_t aidx = ((size_t)(bg0 + ab) * 512 + p0n + ap) * 2;
            ax0 = xg[aidx]; ax1 = xg[aidx + 1];
            const float* gsrc = wg + (((size_t)(p0n + wave) * 512 + n0) << 3) + (lane << 3);
            bw0 = *(const float4*)gsrc; bw1 = *(const float4*)(gsrc + 4);
        }
        #pragma unroll
        for (int ks = 0; ks < 2; ++ks) {
            const int cb = ks * 4 + q;
            short8 a[2], bfr[2];
            #pragma unroll
            for (int fm = 0; fm < 2; ++fm) {
                const int row = wm * 32 + fm * 16 + l15;
                a[fm] = *(const short8*)&As[row * 64 + ((cb ^ (l15 & 7)) << 3)];
            }
            #pragma unroll
            for (int fn = 0; fn < 2; ++fn) {
                const int nl = wnn * 32 + fn * 16 + l15;
                bfr[fn] = *(const short8*)&Bs[((cb * 64) + nl) << 3];
            }
            #pragma unroll
            for (int fm = 0; fm < 2; ++fm)
                #pragma unroll
                for (int fn = 0; fn < 2; ++fn)
                    acc[fm][fn] = __builtin_amdgcn_mfma_f32_16x16x32_bf16(a[fm], bfr[fn], acc[fm][fn], 0, 0, 0);
        }
    }
    #pragma unroll
    for (int fm = 0; fm < 2; ++fm)
        #pragma unroll
        for (int fn = 0; fn < 2; ++fn) {
            const int n = n0 + wnn * 32 + fn * 16 + l15;
            #pragma unroll
            for (int r = 0; r < 4; ++r) {
                const int m = m0 + wm * 32 + fm * 16 + q * 4 + r;
                const int bi = m >> 3, k = m & 7;
                out[(size_t)bi * 4096 + n * 8 + k] = acc[fm][fn][r] + bias[n * 8 + k];
            }
        }
}

extern "C" void kernel_launch(void* const* d_in, const int* in_sizes, int n_in,
                              void* d_out, int out_size, void* d_ws, size_t ws_size,
                              hipStream_t stream) {
    const float* x  = (const float*)d_in[0];
    const float* W  = (const float*)d_in[1];
    const float* bb = (const float*)d_in[2];
    float* out = (float*)d_out;

    const size_t abytes = (size_t)1024 * 2048 * sizeof(unsigned short);  // 4 MB
    const size_t bbytes = (size_t)2048 * 2048 * sizeof(unsigned short);  // 8 MB
    if (ws_size >= abytes + bbytes) {
        unsigned short* Abuf = (unsigned short*)d_ws;
        unsigned short* Bbuf = (unsigned short*)((char*)d_ws + abytes);
        pack_x<<<512, 256, 0, stream>>>(x, Abuf);
        pack_w<<<256, 256, 0, stream>>>(W, Bbuf);
        iso_gemm<<<dim3(16, 16), 512, 0, stream>>>(Abuf, Bbuf, bb, out);
    } else {
        gp_linear_legacy<<<dim3(8, 32), dim3(512), 0, stream>>>(x, W, bb, out);
    }
}